// Round 4
// baseline (794.189 us; speedup 1.0000x reference)
//
#include <hip/hip_runtime.h>

// MoE top-2 of 8 experts. T=4096, D=1024, F=3584.
// Full path: preconvert weights bf16 (one fused kernel), m97-style GEMMs with
// global_load_lds; GEMM2 split-K=4 with fp32 atomicAdd into slot buffer
// (R3 lesson: GEMM2 had 576 blocks x 112 barrier-drain iters -> latency-bound,
// MfmaUtil 13%). Fallback path (~85MB ws): round-2 inline-convert kernels.

#define T_TOK 4096
#define D_DIM 1024
#define F_DIM 3584
#define E_NUM 8
#define N13   (2 * F_DIM)   // 7168: w1/w3 interleaved in 16-row blocks
#define BM 128
#define BN 128
#define BK 32
#define KSPL 4              // gemm2 split-K factor
#define KCH  (F_DIM / KSPL) // 896
#define LDK (BK + 8)        // legacy kernels only

typedef __bf16 bf16x8 __attribute__((ext_vector_type(8)));
typedef float  f32x4  __attribute__((ext_vector_type(4)));

__device__ __forceinline__ unsigned f2bf_u(float f) {
    unsigned u = __builtin_bit_cast(unsigned, f);
    return (u + 0x7FFFu + ((u >> 16) & 1u)) >> 16;   // RNE
}
__device__ __forceinline__ unsigned pack2(float lo, float hi) {
    return f2bf_u(lo) | (f2bf_u(hi) << 16);
}
__device__ __forceinline__ int expert_off(const int* __restrict__ counts, int e) {
    int off = 0;
    for (int i = 0; i < e; i++) off += (counts[i] + BM - 1) & ~(BM - 1);
    return off;
}
__device__ __forceinline__ void load_lds16(const void* g, void* l) {
    __builtin_amdgcn_global_load_lds(
        (const __attribute__((address_space(1))) unsigned*)g,
        (__attribute__((address_space(3))) unsigned*)l, 16, 0, 0);
}

// ---------------------------------------------------------------------------
// Router: 1 wave/token. logits fp32; tok entry = (t<<1)|slot.
// ---------------------------------------------------------------------------
__global__ __launch_bounds__(256)
void router(const float* __restrict__ x, const float* __restrict__ gw,
            float* __restrict__ logits, int* __restrict__ counts,
            int* __restrict__ tok, float* __restrict__ wgt)
{
    const int wave = threadIdx.x >> 6;
    const int lane = threadIdx.x & 63;
    const int t = blockIdx.x * 4 + wave;

    const float* xt = x + (size_t)t * D_DIM + lane * 16;
    float4 xv[4];
#pragma unroll
    for (int i = 0; i < 4; i++) xv[i] = ((const float4*)xt)[i];

    float l[E_NUM];
#pragma unroll
    for (int e = 0; e < E_NUM; e++) {
        const float4* gp = (const float4*)(gw + (size_t)e * D_DIM + lane * 16);
        float d = 0.f;
#pragma unroll
        for (int i = 0; i < 4; i++) {
            float4 g = gp[i];
            d += xv[i].x * g.x + xv[i].y * g.y + xv[i].z * g.z + xv[i].w * g.w;
        }
#pragma unroll
        for (int off = 32; off; off >>= 1) d += __shfl_xor(d, off);
        l[e] = d;
    }
#pragma unroll
    for (int e = 0; e < E_NUM; e++)
        if (lane == e) logits[(size_t)t * E_NUM + e] = l[e];

    int e0 = 0; float v0 = l[0];
#pragma unroll
    for (int e = 1; e < E_NUM; e++) if (l[e] > v0) { v0 = l[e]; e0 = e; }
    int e1 = 0; float v1 = -3.4e38f;
#pragma unroll
    for (int e = 0; e < E_NUM; e++) if (e != e0 && l[e] > v1) { v1 = l[e]; e1 = e; }
    const float p1 = __expf(v1 - v0);
    const float w0 = 1.f / (1.f + p1);
    const float w1 = p1 * w0;

    if (lane < 2) {
        const int   ek = lane ? e1 : e0;
        const float wk = lane ? w1 : w0;
        const int pos = atomicAdd(&counts[ek], 1);
        tok[ek * T_TOK + pos] = (t << 1) | lane;
        wgt[ek * T_TOK + pos] = wk;
    }
}

// ---------------------------------------------------------------------------
// Gather: compacted bf16 rows Xe = x[t]*w, zero padding to 128-multiples.
// ---------------------------------------------------------------------------
__global__ __launch_bounds__(256)
void gather(const float* __restrict__ x, const int* __restrict__ counts,
            const int* __restrict__ tok, const float* __restrict__ wgt,
            unsigned short* __restrict__ Xe)
{
    const int e = blockIdx.y;
    const int cnt = counts[e];
    const int cntpad = (cnt + BM - 1) & ~(BM - 1);
    const int r0 = blockIdx.x * BM;
    if (r0 >= cntpad) return;
    const int moff = expert_off(counts, e);

    const int tid = threadIdx.x;
    const int chunk = tid & 63;
    const int rsub = tid >> 6;
#pragma unroll
    for (int i = 0; i < 32; i++) {
        const int r = r0 + rsub + i * 4;
        unsigned short* dst = Xe + (size_t)(moff + r) * D_DIM + chunk * 16;
        uint4 o0 = {0,0,0,0}, o1 = {0,0,0,0};
        if (r < cnt) {
            const int t = tok[e * T_TOK + r] >> 1;
            const float w = wgt[e * T_TOK + r];
            const float4* src = (const float4*)(x + (size_t)t * D_DIM + chunk * 16);
            float4 a = src[0], b = src[1], c = src[2], d = src[3];
            o0.x = pack2(a.x*w, a.y*w); o0.y = pack2(a.z*w, a.w*w);
            o0.z = pack2(b.x*w, b.y*w); o0.w = pack2(b.z*w, b.w*w);
            o1.x = pack2(c.x*w, c.y*w); o1.y = pack2(c.z*w, c.w*w);
            o1.z = pack2(d.x*w, d.y*w); o1.w = pack2(d.z*w, d.w*w);
        }
        ((uint4*)dst)[0] = o0; ((uint4*)dst)[1] = o1;
    }
}

// ---------------------------------------------------------------------------
// Fused weight preconversion (memory-bound). First region: W13 interleaved;
// second: W2 linear.
// ---------------------------------------------------------------------------
#define W13_CHUNKS ((size_t)E_NUM * N13 * D_DIM / 8)   // 7,340,032
#define W2_CHUNKS  ((size_t)E_NUM * D_DIM * F_DIM / 8) // 3,670,016

__global__ __launch_bounds__(256)
void conv_weights(const float* __restrict__ w1, const float* __restrict__ w3,
                  const float* __restrict__ w2,
                  unsigned short* __restrict__ W13, unsigned short* __restrict__ W2b)
{
    size_t idx = (size_t)blockIdx.x * 256 + threadIdx.x;
    const float* src;
    unsigned short* dst;
    if (idx < W13_CHUNKS) {
        const size_t c = idx * 8;
        const int col = (int)(c & (D_DIM - 1));
        const int r   = (int)(c >> 10);
        const int e   = r / N13;
        const int ng  = r - e * N13;
        const int blk = ng >> 5, rem = ng & 31;
        src = ((rem < 16) ? w1 : w3)
            + ((size_t)e * F_DIM + blk * 16 + (rem & 15)) * D_DIM + col;
        dst = W13 + c;
    } else {
        const size_t c = (idx - W13_CHUNKS) * 8;
        src = w2 + c;
        dst = W2b + c;
    }
    float4 a = ((const float4*)src)[0], b = ((const float4*)src)[1];
    uint4 o;
    o.x = pack2(a.x, a.y); o.y = pack2(a.z, a.w);
    o.z = pack2(b.x, b.y); o.w = pack2(b.z, b.w);
    *(uint4*)dst = o;
}

// ---------------------------------------------------------------------------
// GEMM1 (bf16 weights): H = SwiGLU(Xe x W13^T). m97-style staging.
// ---------------------------------------------------------------------------
__global__ __launch_bounds__(256)
void gemm1_bf(const unsigned short* __restrict__ Xe,
              const unsigned short* __restrict__ W13,
              const int* __restrict__ counts, unsigned short* __restrict__ H)
{
    const int e = blockIdx.z;
    const int cnt = counts[e];
    const int m0 = blockIdx.y * BM;
    if (m0 >= cnt) return;
    const int moff = expert_off(counts, e);
    const int n0 = blockIdx.x * BN;

    __shared__ unsigned short As[BM * BK];
    __shared__ unsigned short Bs[BN * BK];

    const int tid = threadIdx.x, lane = tid & 63, wave = tid >> 6;
    const int wm = (wave >> 1) * 64, wn = (wave & 1) * 64;

    const int lrow = lane >> 2, lch = (lane & 3) * 8;
    const unsigned short* gA0 = Xe + (size_t)(moff + m0 + wave * 16 + lrow) * D_DIM + lch;
    const unsigned short* gA1 = gA0 + (size_t)64 * D_DIM;
    const unsigned short* gB0 = W13 + ((size_t)e * N13 + n0 + wave * 16 + lrow) * D_DIM + lch;
    const unsigned short* gB1 = gB0 + (size_t)64 * D_DIM;
    unsigned short* lA0 = &As[(wave * 16) * BK];
    unsigned short* lA1 = &As[(64 + wave * 16) * BK];
    unsigned short* lB0 = &Bs[(wave * 16) * BK];
    unsigned short* lB1 = &Bs[(64 + wave * 16) * BK];

    f32x4 acc[4][4] = {};
    const int ko = (lane >> 4) * 8;
    const int mr = wm + (lane & 15), nr = wn + (lane & 15);

    for (int k0 = 0; k0 < D_DIM; k0 += BK) {
        load_lds16(gA0, lA0); load_lds16(gA1, lA1);
        load_lds16(gB0, lB0); load_lds16(gB1, lB1);
        gA0 += BK; gA1 += BK; gB0 += BK; gB1 += BK;
        __syncthreads();

        bf16x8 af[4], bfm[4];
#pragma unroll
        for (int i = 0; i < 4; i++) {
            af[i]  = *(const bf16x8*)&As[(mr + i * 16) * BK + ko];
            bfm[i] = *(const bf16x8*)&Bs[(nr + i * 16) * BK + ko];
        }
#pragma unroll
        for (int mi = 0; mi < 4; mi++)
#pragma unroll
            for (int ni = 0; ni < 4; ni++)
                acc[mi][ni] = __builtin_amdgcn_mfma_f32_16x16x32_bf16(
                    af[mi], bfm[ni], acc[mi][ni], 0, 0, 0);
        __syncthreads();
    }

    const int fb = ((n0 + wn) >> 1) + (lane & 15);
#pragma unroll
    for (int mi = 0; mi < 4; mi++) {
        const int mrow = moff + m0 + wm + mi * 16 + ((lane >> 4) << 2);
#pragma unroll
        for (int p = 0; p < 2; p++) {
            f32x4 g = acc[mi][2 * p];
            f32x4 u = acc[mi][2 * p + 1];
            const int f = fb + p * 16;
#pragma unroll
            for (int r = 0; r < 4; r++) {
                float gv = g[r];
                float hv = (gv / (1.f + __expf(-gv))) * u[r];
                H[(size_t)(mrow + r) * F_DIM + f] = (unsigned short)f2bf_u(hv);
            }
        }
    }
}

// ---------------------------------------------------------------------------
// GEMM2 (bf16 weights), split-K=4: buf[slot][t] += partial(H x W2^T).
// grid.z = expert*KSPL + ksplit. Atomics: each output hit by exactly 4 blocks.
// ---------------------------------------------------------------------------
__global__ __launch_bounds__(256)
void gemm2_bf(const unsigned short* __restrict__ H,
              const unsigned short* __restrict__ W2,
              const int* __restrict__ counts, const int* __restrict__ tok,
              float* __restrict__ buf)
{
    const int e  = blockIdx.z >> 2;
    const int ks = blockIdx.z & (KSPL - 1);
    const int cnt = counts[e];
    const int m0 = blockIdx.y * BM;
    if (m0 >= cnt) return;
    const int moff = expert_off(counts, e);
    const int n0 = blockIdx.x * BN;
    const int* tk = tok + e * T_TOK;
    const int kbase = ks * KCH;

    __shared__ unsigned short As[BM * BK];
    __shared__ unsigned short Bs[BN * BK];

    const int tid = threadIdx.x, lane = tid & 63, wave = tid >> 6;
    const int wm = (wave >> 1) * 64, wn = (wave & 1) * 64;

    const int lrow = lane >> 2, lch = (lane & 3) * 8;
    const unsigned short* gA0 = H + (size_t)(moff + m0 + wave * 16 + lrow) * F_DIM + kbase + lch;
    const unsigned short* gA1 = gA0 + (size_t)64 * F_DIM;
    const unsigned short* gB0 = W2 + ((size_t)e * D_DIM + n0 + wave * 16 + lrow) * F_DIM + kbase + lch;
    const unsigned short* gB1 = gB0 + (size_t)64 * F_DIM;
    unsigned short* lA0 = &As[(wave * 16) * BK];
    unsigned short* lA1 = &As[(64 + wave * 16) * BK];
    unsigned short* lB0 = &Bs[(wave * 16) * BK];
    unsigned short* lB1 = &Bs[(64 + wave * 16) * BK];

    f32x4 acc[4][4] = {};
    const int ko = (lane >> 4) * 8;
    const int mr = wm + (lane & 15), nr = wn + (lane & 15);

    for (int k0 = 0; k0 < KCH; k0 += BK) {
        load_lds16(gA0, lA0); load_lds16(gA1, lA1);
        load_lds16(gB0, lB0); load_lds16(gB1, lB1);
        gA0 += BK; gA1 += BK; gB0 += BK; gB1 += BK;
        __syncthreads();

        bf16x8 af[4], bfm[4];
#pragma unroll
        for (int i = 0; i < 4; i++) {
            af[i]  = *(const bf16x8*)&As[(mr + i * 16) * BK + ko];
            bfm[i] = *(const bf16x8*)&Bs[(nr + i * 16) * BK + ko];
        }
#pragma unroll
        for (int mi = 0; mi < 4; mi++)
#pragma unroll
            for (int ni = 0; ni < 4; ni++)
                acc[mi][ni] = __builtin_amdgcn_mfma_f32_16x16x32_bf16(
                    af[mi], bfm[ni], acc[mi][ni], 0, 0, 0);
        __syncthreads();
    }

#pragma unroll
    for (int mi = 0; mi < 4; mi++) {
        const int mbase = m0 + wm + mi * 16 + ((lane >> 4) << 2);
#pragma unroll
        for (int r = 0; r < 4; r++) {
            const int m = mbase + r;
            if (m < cnt) {
                const int v = tk[m];
                float* orow = buf + ((size_t)(v & 1) * T_TOK + (v >> 1)) * D_DIM
                            + n0 + wn + (lane & 15);
#pragma unroll
                for (int ni = 0; ni < 4; ni++)
                    atomicAdd(orow + ni * 16, acc[mi][ni][r]);
            }
        }
    }
}

__global__ __launch_bounds__(256)
void combine(const float* __restrict__ buf, float* __restrict__ out)
{
    const size_t i = (size_t)blockIdx.x * 256 + threadIdx.x;
    float4 a = ((const float4*)buf)[i];
    float4 b = ((const float4*)(buf + (size_t)T_TOK * D_DIM))[i];
    float4 o = {a.x + b.x, a.y + b.y, a.z + b.z, a.w + b.w};
    ((float4*)out)[i] = o;
}

// ===========================================================================
// Legacy fallback (round-2 kernels, inline fp32->bf16 convert, ~85MB ws)
// ===========================================================================
__global__ __launch_bounds__(256)
void legacy_gemm1(const unsigned short* __restrict__ Xe,
                  const float* __restrict__ w1, const float* __restrict__ w3,
                  const int* __restrict__ counts, unsigned short* __restrict__ H)
{
    const int e = blockIdx.z;
    const int cnt = counts[e];
    const int m0 = blockIdx.y * BM;
    if (m0 >= cnt) return;
    const int moff = expert_off(counts, e);
    const int n0 = blockIdx.x * BN;

    const float* W1 = w1 + (size_t)e * F_DIM * D_DIM;
    const float* W3 = w3 + (size_t)e * F_DIM * D_DIM;

    __shared__ unsigned short As[BM * LDK];
    __shared__ unsigned short Bs[BN * LDK];

    const int tid = threadIdx.x;
    const int lane = tid & 63, wave = tid >> 6;
    const int wm = (wave >> 1) * 64, wn = (wave & 1) * 64;
    const int sr = tid >> 1, sc = (tid & 1) * 16;

    const unsigned short* arow = Xe + (size_t)(moff + m0 + sr) * D_DIM + sc;
    const int ng = n0 + sr;
    const int blk = ng >> 5, rem = ng & 31;
    const float* brow = (rem < 16)
        ? (W1 + (size_t)(blk * 16 + rem) * D_DIM + sc)
        : (W3 + (size_t)(blk * 16 + rem - 16) * D_DIM + sc);

    f32x4 acc[4][4] = {};
    const int ko = (lane >> 4) * 8;
    const int mr = wm + (lane & 15);
    const int nr = wn + (lane & 15);

    for (int k0 = 0; k0 < D_DIM; k0 += BK) {
        uint4 a0 = ((const uint4*)(arow + k0))[0];
        uint4 a1 = ((const uint4*)(arow + k0))[1];
        const float4* bp = (const float4*)(brow + k0);
        float4 b0 = bp[0], b1 = bp[1], b2 = bp[2], b3 = bp[3];
        uint4 pb0, pb1;
        pb0.x = pack2(b0.x, b0.y); pb0.y = pack2(b0.z, b0.w);
        pb0.z = pack2(b1.x, b1.y); pb0.w = pack2(b1.z, b1.w);
        pb1.x = pack2(b2.x, b2.y); pb1.y = pack2(b2.z, b2.w);
        pb1.z = pack2(b3.x, b3.y); pb1.w = pack2(b3.z, b3.w);

        __syncthreads();
        ((uint4*)&As[sr * LDK + sc])[0] = a0;
        ((uint4*)&As[sr * LDK + sc])[1] = a1;
        ((uint4*)&Bs[sr * LDK + sc])[0] = pb0;
        ((uint4*)&Bs[sr * LDK + sc])[1] = pb1;
        __syncthreads();

        bf16x8 af[4], bfm[4];
#pragma unroll
        for (int i = 0; i < 4; i++) {
            af[i]  = *(const bf16x8*)&As[(mr + i * 16) * LDK + ko];
            bfm[i] = *(const bf16x8*)&Bs[(nr + i * 16) * LDK + ko];
        }
#pragma unroll
        for (int mi = 0; mi < 4; mi++)
#pragma unroll
            for (int ni = 0; ni < 4; ni++)
                acc[mi][ni] = __builtin_amdgcn_mfma_f32_16x16x32_bf16(
                    af[mi], bfm[ni], acc[mi][ni], 0, 0, 0);
    }

    const int fb = ((n0 + wn) >> 1) + (lane & 15);
#pragma unroll
    for (int mi = 0; mi < 4; mi++) {
        const int mrow = moff + m0 + wm + mi * 16 + ((lane >> 4) << 2);
#pragma unroll
        for (int p = 0; p < 2; p++) {
            f32x4 g = acc[mi][2 * p];
            f32x4 u = acc[mi][2 * p + 1];
            const int f = fb + p * 16;
#pragma unroll
            for (int r = 0; r < 4; r++) {
                float gv = g[r];
                float hv = (gv / (1.f + __expf(-gv))) * u[r];
                H[(size_t)(mrow + r) * F_DIM + f] = (unsigned short)f2bf_u(hv);
            }
        }
    }
}

__global__ __launch_bounds__(256)
void legacy_gemm2(const unsigned short* __restrict__ H, const float* __restrict__ w2,
                  const int* __restrict__ counts, const int* __restrict__ tok,
                  float* __restrict__ out)
{
    const int e = blockIdx.z;
    const int cnt = counts[e];
    const int m0 = blockIdx.y * BM;
    if (m0 >= cnt) return;
    const int moff = expert_off(counts, e);
    const int n0 = blockIdx.x * BN;

    const float* W2 = w2 + (size_t)e * D_DIM * F_DIM;
    const int* tk = tok + e * T_TOK;

    __shared__ unsigned short As[BM * LDK];
    __shared__ unsigned short Bs[BN * LDK];

    const int tid = threadIdx.x;
    const int lane = tid & 63, wave = tid >> 6;
    const int wm = (wave >> 1) * 64, wn = (wave & 1) * 64;
    const int sr = tid >> 1, sc = (tid & 1) * 16;

    const unsigned short* arow = H + (size_t)(moff + m0 + sr) * F_DIM + sc;
    const float* brow = W2 + (size_t)(n0 + sr) * F_DIM + sc;

    f32x4 acc[4][4] = {};
    const int ko = (lane >> 4) * 8;
    const int mr = wm + (lane & 15);
    const int nr = wn + (lane & 15);

    for (int k0 = 0; k0 < F_DIM; k0 += BK) {
        uint4 a0 = ((const uint4*)(arow + k0))[0];
        uint4 a1 = ((const uint4*)(arow + k0))[1];
        const float4* bp = (const float4*)(brow + k0);
        float4 b0 = bp[0], b1 = bp[1], b2 = bp[2], b3 = bp[3];
        uint4 pb0, pb1;
        pb0.x = pack2(b0.x, b0.y); pb0.y = pack2(b0.z, b0.w);
        pb0.z = pack2(b1.x, b1.y); pb0.w = pack2(b1.z, b1.w);
        pb1.x = pack2(b2.x, b2.y); pb1.y = pack2(b2.z, b2.w);
        pb1.z = pack2(b3.x, b3.y); pb1.w = pack2(b3.z, b3.w);

        __syncthreads();
        ((uint4*)&As[sr * LDK + sc])[0] = a0;
        ((uint4*)&As[sr * LDK + sc])[1] = a1;
        ((uint4*)&Bs[sr * LDK + sc])[0] = pb0;
        ((uint4*)&Bs[sr * LDK + sc])[1] = pb1;
        __syncthreads();

        bf16x8 af[4], bfm[4];
#pragma unroll
        for (int i = 0; i < 4; i++) {
            af[i]  = *(const bf16x8*)&As[(mr + i * 16) * LDK + ko];
            bfm[i] = *(const bf16x8*)&Bs[(nr + i * 16) * LDK + ko];
        }
#pragma unroll
        for (int mi = 0; mi < 4; mi++)
#pragma unroll
            for (int ni = 0; ni < 4; ni++)
                acc[mi][ni] = __builtin_amdgcn_mfma_f32_16x16x32_bf16(
                    af[mi], bfm[ni], acc[mi][ni], 0, 0, 0);
    }

#pragma unroll
    for (int mi = 0; mi < 4; mi++) {
        const int mbase = m0 + wm + mi * 16 + ((lane >> 4) << 2);
#pragma unroll
        for (int r = 0; r < 4; r++) {
            const int m = mbase + r;
            if (m < cnt) {
                const int t = tk[m] >> 1;
                float* orow = out + (size_t)t * D_DIM + n0 + wn + (lane & 15);
#pragma unroll
                for (int ni = 0; ni < 4; ni++)
                    atomicAdd(orow + ni * 16, acc[mi][ni][r]);
            }
        }
    }
}

// ---------------------------------------------------------------------------
extern "C" void kernel_launch(void* const* d_in, const int* in_sizes, int n_in,
                              void* d_out, int out_size, void* d_ws, size_t ws_size,
                              hipStream_t stream)
{
    const float* x  = (const float*)d_in[0];
    const float* gw = (const float*)d_in[1];
    const float* w1 = (const float*)d_in[2];
    const float* w3 = (const float*)d_in[3];
    const float* w2 = (const float*)d_in[4];
    float* out    = (float*)d_out;
    float* logits = out + (size_t)T_TOK * D_DIM;

    char* ws = (char*)d_ws;
    int*   counts = (int*)ws;                               // 256 B
    int*   tok    = (int*)(ws + 256);                       // 128 KB
    float* wgt    = (float*)(ws + 131328);                  // 128 KB
    unsigned short* Xe = (unsigned short*)(ws + 262400);    // 18,874,368
    unsigned short* H  = (unsigned short*)(ws + 19136768);  // 66,060,288
    float*          buf = (float*)(ws + 85197056);          // 33,554,432
    unsigned short* W13 = (unsigned short*)(ws + 118751488);// 117,440,512
    unsigned short* W2b = (unsigned short*)(ws + 236192000);// 58,720,256
    const size_t NEED_FULL = 294912256;

    hipMemsetAsync(counts, 0, E_NUM * sizeof(int), stream);
    router<<<T_TOK / 4, 256, 0, stream>>>(x, gw, logits, counts, tok, wgt);
    gather<<<dim3(T_TOK / BM, E_NUM), 256, 0, stream>>>(x, counts, tok, wgt, Xe);

    if (ws_size >= NEED_FULL) {
        hipMemsetAsync(buf, 0, 2ull * T_TOK * D_DIM * sizeof(float), stream);
        conv_weights<<<(unsigned)((W13_CHUNKS + W2_CHUNKS) / 256), 256, 0, stream>>>(
            w1, w3, w2, W13, W2b);
        gemm1_bf<<<dim3(N13 / BN, T_TOK / BM, E_NUM), 256, 0, stream>>>(Xe, W13, counts, H);
        gemm2_bf<<<dim3(D_DIM / BN, T_TOK / BM, E_NUM * KSPL), 256, 0, stream>>>(
            H, W2b, counts, tok, buf);
        combine<<<(T_TOK * D_DIM / 4) / 256, 256, 0, stream>>>(buf, out);
    } else {
        hipMemsetAsync(out, 0, (size_t)T_TOK * D_DIM * sizeof(float), stream);
        legacy_gemm1<<<dim3(N13 / BN, T_TOK / BM, E_NUM), 256, 0, stream>>>(Xe, w1, w3, counts, H);
        legacy_gemm2<<<dim3(D_DIM / BN, T_TOK / BM, E_NUM), 256, 0, stream>>>(H, w2, counts, tok, out);
    }
}